// Round 1
// baseline (1729.201 us; speedup 1.0000x reference)
//
#include <hip/hip_runtime.h>

#define T 64
#define F_IN 3
#define H 16
#define G 48
#define D2 32
#define DEPTH 5
#define NCLS 4
// per-batch-element stride in the LDS y buffers, padded (+16 floats) so the
// 4 jobs of the wave hit disjoint/2-way bank groups on broadcast reads.
#define YSTRIDE 2064

__device__ __forceinline__ float fast_sigmoid(float x) {
    return __fdividef(1.0f, 1.0f + __expf(-x));
}
__device__ __forceinline__ float fast_tanh(float x) {
    // tanh(x) = 1 - 2/(1+exp(2x)); saturates correctly at +-inf
    return 1.0f - __fdividef(2.0f, 1.0f + __expf(2.0f * x));
}
__device__ __forceinline__ float dot4(float4 a, float4 b) {
    return a.x*b.x + a.y*b.y + a.z*b.z + a.w*b.w;
}

// One wave (64 threads) per workgroup. 4 jobs per wave: (batch-local, dir)
// = (0,f),(0,b),(1,f),(1,b). 16 lanes per job; lane j owns h[j] and gates
// r_j, z_j, n_j (rows j, 16+j, 32+j of the 48-row gate matrices).
__global__ __launch_bounds__(64, 1) void bigru_all(
    const float* __restrict__ x,
    const float* __restrict__ Wi1, const float* __restrict__ Wh1,
    const float* __restrict__ bi1, const float* __restrict__ bh1,
    const float* __restrict__ Wi5, const float* __restrict__ Wh5,
    const float* __restrict__ bi5, const float* __restrict__ bh5,
    const float* __restrict__ Wc,  const float* __restrict__ bc,
    float* __restrict__ out)
{
    __shared__ __align__(16) float ybuf0[2 * YSTRIDE];
    __shared__ __align__(16) float ybuf1[2 * YSTRIDE];
    __shared__ __align__(16) float hbuf[4 * H];
    __shared__ __align__(16) float xsh[2 * T * 4];   // x staged, padded to 4/step

    const int lane = threadIdx.x;
    const int job  = lane >> 4;    // 0..3
    const int j    = lane & 15;    // h element owned by this lane
    const int lb   = job >> 1;     // local batch element 0/1
    const int dir  = job & 1;      // 0 = fwd, 1 = bwd

    // ---- stage x[2 batch][T][3] into LDS (coalesced: 384 contiguous floats)
    {
        const float* xg = x + (size_t)blockIdx.x * (2 * T * F_IN);
        for (int idx = lane; idx < 2 * T * F_IN; idx += 64) {
            int bb = idx / (T * F_IN);
            int r  = idx - bb * (T * F_IN);
            int tt = r / F_IN;
            int c  = r - tt * F_IN;
            xsh[bb * (T * 4) + tt * 4 + c] = xg[idx];
        }
    }

    float hj;  // this lane's own h element (also mirrored in hbuf)

    // ================= layer 1 (input width 3) =================
    {
        const float* Wi = Wi1 + dir * (G * F_IN);
        const float* Wh = Wh1 + dir * (G * H);
        const float* bi = bi1 + dir * G;
        const float* bh = bh1 + dir * G;
        float  wi[3][F_IN];
        float4 wh4[3][H / 4];
        float  bir[3], bhr[3];
        #pragma unroll
        for (int g = 0; g < 3; ++g) {
            int row = g * H + j;
            #pragma unroll
            for (int k = 0; k < F_IN; ++k) wi[g][k] = Wi[row * F_IN + k];
            #pragma unroll
            for (int k = 0; k < H / 4; ++k)
                wh4[g][k] = ((const float4*)(Wh + row * H))[k];
            bir[g] = bi[row];
            bhr[g] = bh[row];
        }
        hj = 0.0f;
        hbuf[job * H + j] = 0.0f;
        __syncthreads();  // also covers xsh staging

        float* yo = ybuf0 + lb * YSTRIDE;
        const float4* x4 = ((const float4*)xsh) + lb * T;
        const float4* h4 = (const float4*)(hbuf + job * H);

        #pragma unroll 1
        for (int s = 0; s < T; ++s) {
            int t = dir ? (T - 1 - s) : s;
            float4 xv = x4[t];
            float gx0 = bir[0] + wi[0][0]*xv.x + wi[0][1]*xv.y + wi[0][2]*xv.z;
            float gx1 = bir[1] + wi[1][0]*xv.x + wi[1][1]*xv.y + wi[1][2]*xv.z;
            float gx2 = bir[2] + wi[2][0]*xv.x + wi[2][1]*xv.y + wi[2][2]*xv.z;
            float4 hv0 = h4[0], hv1 = h4[1], hv2 = h4[2], hv3 = h4[3];
            float gh0 = bhr[0] + dot4(wh4[0][0],hv0) + dot4(wh4[0][1],hv1)
                                + dot4(wh4[0][2],hv2) + dot4(wh4[0][3],hv3);
            float gh1 = bhr[1] + dot4(wh4[1][0],hv0) + dot4(wh4[1][1],hv1)
                                + dot4(wh4[1][2],hv2) + dot4(wh4[1][3],hv3);
            float gh2 = bhr[2] + dot4(wh4[2][0],hv0) + dot4(wh4[2][1],hv1)
                                + dot4(wh4[2][2],hv2) + dot4(wh4[2][3],hv3);
            float r = fast_sigmoid(gx0 + gh0);
            float z = fast_sigmoid(gx1 + gh1);
            float n = fast_tanh(gx2 + r * gh2);
            float hn = (1.0f - z) * n + z * hj;
            hj = hn;
            hbuf[job * H + j] = hn;
            yo[t * D2 + dir * H + j] = hn;
            __syncthreads();
        }
    }

    // ================= layers 2..6 (input width 32) =================
    #pragma unroll 1
    for (int l = 0; l < DEPTH; ++l) {
        const int pl = l * 2 + dir;
        const float* Wi = Wi5 + (size_t)pl * (G * D2);
        const float* Wh = Wh5 + (size_t)pl * (G * H);
        const float* bi = bi5 + pl * G;
        const float* bh = bh5 + pl * G;
        float4 wi4[3][D2 / 4];
        float4 wh4[3][H / 4];
        float  bir[3], bhr[3];
        #pragma unroll
        for (int g = 0; g < 3; ++g) {
            int row = g * H + j;
            #pragma unroll
            for (int k = 0; k < D2 / 4; ++k)
                wi4[g][k] = ((const float4*)(Wi + row * D2))[k];
            #pragma unroll
            for (int k = 0; k < H / 4; ++k)
                wh4[g][k] = ((const float4*)(Wh + row * H))[k];
            bir[g] = bi[row];
            bhr[g] = bh[row];
        }
        const float* yin = (l & 1) ? ybuf1 : ybuf0;
        float*       yo  = (l & 1) ? ybuf0 : ybuf1;

        hj = 0.0f;
        hbuf[job * H + j] = 0.0f;
        __syncthreads();

        const float4* h4 = (const float4*)(hbuf + job * H);
        const float*  yb = yin + lb * YSTRIDE;
        float*       yob = yo  + lb * YSTRIDE;

        #pragma unroll 1
        for (int s = 0; s < T; ++s) {
            int t = dir ? (T - 1 - s) : s;
            const float4* y4 = (const float4*)(yb + t * D2);
            float gx0 = bir[0], gx1 = bir[1], gx2 = bir[2];
            #pragma unroll
            for (int k = 0; k < D2 / 4; ++k) {
                float4 v = y4[k];
                gx0 += dot4(wi4[0][k], v);
                gx1 += dot4(wi4[1][k], v);
                gx2 += dot4(wi4[2][k], v);
            }
            float4 hv0 = h4[0], hv1 = h4[1], hv2 = h4[2], hv3 = h4[3];
            float gh0 = bhr[0] + dot4(wh4[0][0],hv0) + dot4(wh4[0][1],hv1)
                                + dot4(wh4[0][2],hv2) + dot4(wh4[0][3],hv3);
            float gh1 = bhr[1] + dot4(wh4[1][0],hv0) + dot4(wh4[1][1],hv1)
                                + dot4(wh4[1][2],hv2) + dot4(wh4[1][3],hv3);
            float gh2 = bhr[2] + dot4(wh4[2][0],hv0) + dot4(wh4[2][1],hv1)
                                + dot4(wh4[2][2],hv2) + dot4(wh4[2][3],hv3);
            float r = fast_sigmoid(gx0 + gh0);
            float z = fast_sigmoid(gx1 + gh1);
            float n = fast_tanh(gx2 + r * gh2);
            float hn = (1.0f - z) * n + z * hj;
            hj = hn;
            hbuf[job * H + j] = hn;
            yob[t * D2 + dir * H + j] = hn;
            __syncthreads();
        }
    }

    // ================= classifier + softmax =================
    // final y lives in ybuf1 (DEPTH=5: last write was l=4 -> ybuf1)
    #pragma unroll
    for (int i = 0; i < 2; ++i) {
        int idx = lane + i * 64;          // 0..127 -> (bb, t)
        int bb  = idx >> 6;
        int t   = idx & 63;
        const float4* y4 = (const float4*)(ybuf1 + bb * YSTRIDE + t * D2);
        float lg[NCLS];
        #pragma unroll
        for (int c = 0; c < NCLS; ++c) {
            const float4* wc4 = (const float4*)(Wc + c * D2);
            float acc = bc[c];
            #pragma unroll
            for (int k = 0; k < D2 / 4; ++k) acc += dot4(wc4[k], y4[k]);
            lg[c] = acc;
        }
        float m = fmaxf(fmaxf(lg[0], lg[1]), fmaxf(lg[2], lg[3]));
        float e0 = __expf(lg[0] - m), e1 = __expf(lg[1] - m);
        float e2 = __expf(lg[2] - m), e3 = __expf(lg[3] - m);
        float inv = __fdividef(1.0f, e0 + e1 + e2 + e3);
        size_t bglob = (size_t)blockIdx.x * 2 + bb;
        float4 o;
        o.x = e0 * inv; o.y = e1 * inv; o.z = e2 * inv; o.w = e3 * inv;
        ((float4*)out)[bglob * T + t] = o;
    }
}

extern "C" void kernel_launch(void* const* d_in, const int* in_sizes, int n_in,
                              void* d_out, int out_size, void* d_ws, size_t ws_size,
                              hipStream_t stream) {
    const float* x   = (const float*)d_in[0];
    const float* Wi1 = (const float*)d_in[1];
    const float* Wh1 = (const float*)d_in[2];
    const float* bi1 = (const float*)d_in[3];
    const float* bh1 = (const float*)d_in[4];
    const float* Wi5 = (const float*)d_in[5];
    const float* Wh5 = (const float*)d_in[6];
    const float* bi5 = (const float*)d_in[7];
    const float* bh5 = (const float*)d_in[8];
    const float* Wc  = (const float*)d_in[9];
    const float* bc  = (const float*)d_in[10];
    float* out = (float*)d_out;

    const int B = in_sizes[0] / (T * F_IN);   // 16384
    dim3 grid(B / 2), block(64);
    hipLaunchKernelGGL(bigru_all, grid, block, 0, stream,
                       x, Wi1, Wh1, bi1, bh1, Wi5, Wh5, bi5, bh5, Wc, bc, out);
}

// Round 2
// 1075.300 us; speedup vs baseline: 1.6081x; 1.6081x over previous
//
#include <hip/hip_runtime.h>

#define T 64
#define F_IN 3
#define H 16
#define G 48
#define D2 32
#define DEPTH 5
#define NCLS 4
#define TC 16               // xp chunk length (timesteps)

// LDS geometry (element units)
#define YST 40              // f16 per t-row (32 data + 8 pad -> bank spread, 16B aligned)
#define YSB 2568            // f16 per batch elem (64*40 + 8 pad)
#define XP_T 64             // f32 words per tloc (16 j * 4)
#define XP_JOB 1032         // f32 words per job (16*64 + 8 pad)
#define HB_JOB 20           // f32 per job in hbuf (16 + 4 pad)

typedef _Float16 half8 __attribute__((ext_vector_type(8)));
typedef float f32x4v __attribute__((ext_vector_type(4)));

__device__ __forceinline__ float fast_sigmoid(float x) {
    return __fdividef(1.0f, 1.0f + __expf(-x));
}
__device__ __forceinline__ float fast_tanh(float x) {
    return 1.0f - __fdividef(2.0f, 1.0f + __expf(2.0f * x));
}
__device__ __forceinline__ float dot4f(float4 a, float4 b, float acc) {
    acc = fmaf(a.x, b.x, acc); acc = fmaf(a.y, b.y, acc);
    acc = fmaf(a.z, b.z, acc); acc = fmaf(a.w, b.w, acc);
    return acc;
}

// One wave (64 threads) per WG; 4 jobs = (2 local batch) x (2 dir); 16 lanes/job,
// lane j owns h[j] and gate rows {j, 16+j, 32+j}.
// Per layer (2..6): xp = y_in @ Wi^T + bi precomputed in 16-step chunks via
// f16 MFMA (A: y tile, B: Wi rows), recurrence keeps only Wh.h on VALU.
__global__ __launch_bounds__(64, 1) void bigru_all(
    const float* __restrict__ x,
    const float* __restrict__ Wi1, const float* __restrict__ Wh1,
    const float* __restrict__ bi1, const float* __restrict__ bh1,
    const float* __restrict__ Wi5, const float* __restrict__ Wh5,
    const float* __restrict__ bi5, const float* __restrict__ bh5,
    const float* __restrict__ Wc,  const float* __restrict__ bc,
    float* __restrict__ out)
{
    __shared__ __align__(16) _Float16 yb0[2 * YSB];
    __shared__ __align__(16) _Float16 yb1[2 * YSB];
    __shared__ __align__(16) float    xp[4 * XP_JOB];
    __shared__ __align__(16) float    hb[4 * HB_JOB];
    __shared__ __align__(16) float    xs[2 * T * 4];

    const int lane = threadIdx.x;
    const int j15  = lane & 15;
    const int quad = lane >> 4;
    const int job  = quad;          // 0..3
    const int lb   = job >> 1;      // local batch 0/1
    const int dir  = job & 1;       // 0 fwd, 1 bwd

    // ---- stage x[2][T][3] -> xs[2][T][4]
    {
        const float* xg = x + (size_t)blockIdx.x * (2 * T * F_IN);
        for (int idx = lane; idx < 2 * T * F_IN; idx += 64) {
            int bb = idx / (T * F_IN);
            int r  = idx - bb * (T * F_IN);
            int tt = r / F_IN;
            int c  = r - tt * F_IN;
            xs[bb * (T * 4) + tt * 4 + c] = xg[idx];
        }
    }

    float hj;

    // ================= layer 1 (input width 3, VALU gx) =================
    {
        const float* Wi = Wi1 + dir * (G * F_IN);
        const float* Wh = Wh1 + dir * (G * H);
        const float* bi = bi1 + dir * G;
        const float* bh = bh1 + dir * G;
        float  wi[3][F_IN];
        float4 wh4[3][4];
        float  bir[3], bhr[3];
        #pragma unroll
        for (int g = 0; g < 3; ++g) {
            int row = g * H + j15;
            #pragma unroll
            for (int k = 0; k < F_IN; ++k) wi[g][k] = Wi[row * F_IN + k];
            #pragma unroll
            for (int k = 0; k < 4; ++k)
                wh4[g][k] = ((const float4*)(Wh + row * H))[k];
            bir[g] = bi[row];
            bhr[g] = bh[row];
        }
        hj = 0.0f;
        hb[job * HB_JOB + j15] = 0.0f;
        __syncthreads();   // covers xs staging + hb init

        const float4* x4  = ((const float4*)xs) + lb * T;
        const float4* h4p = (const float4*)(hb + job * HB_JOB);
        _Float16* yw = yb0 + lb * YSB + (dir ? (T - 1) : 0) * YST + dir * H + j15;
        const int ystep = dir ? -YST : YST;

        #pragma unroll 2
        for (int s = 0; s < T; ++s) {
            int t = dir ? (T - 1 - s) : s;
            float4 xv = x4[t];
            float gx0 = fmaf(wi[0][2], xv.z, fmaf(wi[0][1], xv.y, fmaf(wi[0][0], xv.x, bir[0])));
            float gx1 = fmaf(wi[1][2], xv.z, fmaf(wi[1][1], xv.y, fmaf(wi[1][0], xv.x, bir[1])));
            float gx2 = fmaf(wi[2][2], xv.z, fmaf(wi[2][1], xv.y, fmaf(wi[2][0], xv.x, bir[2])));
            float4 hv0 = h4p[0], hv1 = h4p[1], hv2 = h4p[2], hv3 = h4p[3];
            float gh0 = dot4f(wh4[0][3], hv3, dot4f(wh4[0][2], hv2, dot4f(wh4[0][1], hv1, dot4f(wh4[0][0], hv0, bhr[0]))));
            float gh1 = dot4f(wh4[1][3], hv3, dot4f(wh4[1][2], hv2, dot4f(wh4[1][1], hv1, dot4f(wh4[1][0], hv0, bhr[1]))));
            float gh2 = dot4f(wh4[2][3], hv3, dot4f(wh4[2][2], hv2, dot4f(wh4[2][1], hv1, dot4f(wh4[2][0], hv0, bhr[2]))));
            float rg = fast_sigmoid(gx0 + gh0);
            float zg = fast_sigmoid(gx1 + gh1);
            float ng = fast_tanh(fmaf(rg, gh2, gx2));
            float hn = fmaf(zg, hj - ng, ng);
            hj = hn;
            hb[job * HB_JOB + j15] = hn;
            *yw = (_Float16)hn;
            yw += ystep;
            __syncthreads();
        }
    }

    // ================= layers 2..6: MFMA xp + slim recurrence =================
    #pragma unroll 1
    for (int l = 0; l < DEPTH; ++l) {
        const _Float16* yin  = (l & 1) ? yb1 : yb0;
        _Float16*       yout = (l & 1) ? yb0 : yb1;

        // B-frags: bf[d][nt] holds Wi_d[nt*16 + j15][quad*8 + 0..7] as f16
        half8 bf[2][3];
        float bib[2][3];
        #pragma unroll
        for (int d = 0; d < 2; ++d) {
            #pragma unroll
            for (int nt = 0; nt < 3; ++nt) {
                const float* w = Wi5 + ((size_t)(l * 2 + d) * G + nt * 16 + j15) * D2 + quad * 8;
                half8 hv;
                #pragma unroll
                for (int i = 0; i < 8; ++i) hv[i] = (_Float16)w[i];
                bf[d][nt] = hv;
                bib[d][nt] = bi5[(l * 2 + d) * G + nt * 16 + j15];
            }
        }
        // recurrent weights for this lane's own job
        float4 wh4[3][4];
        float  bhr[3];
        {
            const float* WhL = Wh5 + (size_t)(l * 2 + dir) * G * H;
            const float* bhL = bh5 + (l * 2 + dir) * G;
            #pragma unroll
            for (int g = 0; g < 3; ++g) {
                int row = g * H + j15;
                #pragma unroll
                for (int k = 0; k < 4; ++k)
                    wh4[g][k] = ((const float4*)(WhL + row * H))[k];
                bhr[g] = bhL[row];
            }
        }
        hj = 0.0f;
        hb[job * HB_JOB + j15] = 0.0f;
        __syncthreads();

        #pragma unroll 1
        for (int c = 0; c < 4; ++c) {
            const int s0 = c * TC;
            // ---- xp chunk via MFMA: for each job, XP[tb..tb+15][0..47] ----
            #pragma unroll
            for (int jb = 0; jb < 4; ++jb) {
                const int db = jb & 1, bb = jb >> 1;
                const int tb = db ? (T - TC - s0) : s0;
                half8 a = *(const half8*)(yin + bb * YSB + (tb + j15) * YST + quad * 8);
                f32x4v c0 = {0.f,0.f,0.f,0.f}, c1 = {0.f,0.f,0.f,0.f}, c2 = {0.f,0.f,0.f,0.f};
                c0 = __builtin_amdgcn_mfma_f32_16x16x32_f16(a, bf[db][0], c0, 0, 0, 0);
                c1 = __builtin_amdgcn_mfma_f32_16x16x32_f16(a, bf[db][1], c1, 0, 0, 0);
                c2 = __builtin_amdgcn_mfma_f32_16x16x32_f16(a, bf[db][2], c2, 0, 0, 0);
                // C layout: col = j15 = gate-within-tile, row = quad*4+r = t-tb
                float* xw = xp + jb * XP_JOB + (quad * 4) * XP_T + j15 * 4;
                #pragma unroll
                for (int r = 0; r < 4; ++r) {
                    float4 v;
                    v.x = c0[r] + bib[db][0];
                    v.y = c1[r] + bib[db][1];
                    v.z = c2[r] + bib[db][2];
                    v.w = 0.0f;
                    *(float4*)(xw + r * XP_T) = v;
                }
            }
            __syncthreads();

            // ---- 16 recurrent steps ----
            const float* xr = xp + job * XP_JOB + (dir ? (TC - 1) : 0) * XP_T + j15 * 4;
            const int t0 = dir ? (T - 1 - s0) : s0;
            _Float16* yw = yout + lb * YSB + t0 * YST + dir * H + j15;
            const int xstep = dir ? -XP_T : XP_T;
            const int ystep = dir ? -YST : YST;
            const float4* h4p = (const float4*)(hb + job * HB_JOB);

            #pragma unroll 2
            for (int cl = 0; cl < TC; ++cl) {
                float4 gx = *(const float4*)xr;
                float4 hv0 = h4p[0], hv1 = h4p[1], hv2 = h4p[2], hv3 = h4p[3];
                float gh0 = dot4f(wh4[0][3], hv3, dot4f(wh4[0][2], hv2, dot4f(wh4[0][1], hv1, dot4f(wh4[0][0], hv0, bhr[0]))));
                float gh1 = dot4f(wh4[1][3], hv3, dot4f(wh4[1][2], hv2, dot4f(wh4[1][1], hv1, dot4f(wh4[1][0], hv0, bhr[1]))));
                float gh2 = dot4f(wh4[2][3], hv3, dot4f(wh4[2][2], hv2, dot4f(wh4[2][1], hv1, dot4f(wh4[2][0], hv0, bhr[2]))));
                float rg = fast_sigmoid(gx.x + gh0);
                float zg = fast_sigmoid(gx.y + gh1);
                float ng = fast_tanh(fmaf(rg, gh2, gx.z));
                float hn = fmaf(zg, hj - ng, ng);
                hj = hn;
                hb[job * HB_JOB + j15] = hn;
                *yw = (_Float16)hn;
                xr += xstep;
                yw += ystep;
                __syncthreads();
            }
        }
    }

    // ================= classifier + softmax (final y in yb1) =================
    #pragma unroll
    for (int i = 0; i < 2; ++i) {
        int idx = lane + i * 64;
        int bb  = idx >> 6;
        int t   = idx & 63;
        const _Float16* yrow = yb1 + bb * YSB + t * YST;
        float yv[D2];
        #pragma unroll
        for (int k = 0; k < D2; ++k) yv[k] = (float)yrow[k];
        float lg[NCLS];
        #pragma unroll
        for (int c = 0; c < NCLS; ++c) {
            const float* wc = Wc + c * D2;
            float acc = bc[c];
            #pragma unroll
            for (int k = 0; k < D2; ++k) acc = fmaf(wc[k], yv[k], acc);
            lg[c] = acc;
        }
        float m = fmaxf(fmaxf(lg[0], lg[1]), fmaxf(lg[2], lg[3]));
        float e0 = __expf(lg[0] - m), e1 = __expf(lg[1] - m);
        float e2 = __expf(lg[2] - m), e3 = __expf(lg[3] - m);
        float inv = __fdividef(1.0f, e0 + e1 + e2 + e3);
        size_t bglob = (size_t)blockIdx.x * 2 + bb;
        float4 o;
        o.x = e0 * inv; o.y = e1 * inv; o.z = e2 * inv; o.w = e3 * inv;
        ((float4*)out)[bglob * T + t] = o;
    }
}

extern "C" void kernel_launch(void* const* d_in, const int* in_sizes, int n_in,
                              void* d_out, int out_size, void* d_ws, size_t ws_size,
                              hipStream_t stream) {
    const float* x   = (const float*)d_in[0];
    const float* Wi1 = (const float*)d_in[1];
    const float* Wh1 = (const float*)d_in[2];
    const float* bi1 = (const float*)d_in[3];
    const float* bh1 = (const float*)d_in[4];
    const float* Wi5 = (const float*)d_in[5];
    const float* Wh5 = (const float*)d_in[6];
    const float* bi5 = (const float*)d_in[7];
    const float* bh5 = (const float*)d_in[8];
    const float* Wc  = (const float*)d_in[9];
    const float* bc  = (const float*)d_in[10];
    float* out = (float*)d_out;

    const int B = in_sizes[0] / (T * F_IN);   // 16384
    dim3 grid(B / 2), block(64);
    hipLaunchKernelGGL(bigru_all, grid, block, 0, stream,
                       x, Wi1, Wh1, bi1, bh1, Wi5, Wh5, bi5, bh5, Wc, bc, out);
}

// Round 3
// 986.809 us; speedup vs baseline: 1.7523x; 1.0897x over previous
//
#include <hip/hip_runtime.h>

#define T 64
#define F_IN 3
#define H 16
#define G 48
#define D2 32
#define DEPTH 5
#define NCLS 4
#define TC 16               // xp chunk length (timesteps)

// LDS geometry (element units)
#define YST 40              // f16 per t-row (32 data + 8 pad), 16B-aligned rows
#define YSB 2568            // f16 per batch elem (64*40 + 8 pad)
#define XPJ 1032            // f16 per job in xp: 16 t * 64 (j15*4) + 8 pad, 16B aligned
#define HB_JOB 20           // f32 per job in hbuf (16 + 4 pad)

typedef _Float16 half8 __attribute__((ext_vector_type(8)));
typedef _Float16 half4v __attribute__((ext_vector_type(4)));
typedef float f32x4v __attribute__((ext_vector_type(4)));

__device__ __forceinline__ float fast_sigmoid(float x) {
    return __fdividef(1.0f, 1.0f + __expf(-x));
}
__device__ __forceinline__ float fast_tanh(float x) {
    return 1.0f - __fdividef(2.0f, 1.0f + __expf(2.0f * x));
}
__device__ __forceinline__ float dot4f(float4 a, float4 b, float acc) {
    acc = fmaf(a.x, b.x, acc); acc = fmaf(a.y, b.y, acc);
    acc = fmaf(a.z, b.z, acc); acc = fmaf(a.w, b.w, acc);
    return acc;
}

// One wave (64 threads) per WG; 4 jobs = (2 local batch) x (2 dir); 16 lanes/job,
// lane j owns h[j] and gate rows {j, 16+j, 32+j}.
// NOTE: the whole workgroup is ONE wave -> lockstep. LDS ops from a single wave
// to the same __shared__ array complete in program order, so NO __syncthreads()
// is needed anywhere (h exchange, xp transpose, y ping-pong are all same-wave).
__global__ __launch_bounds__(64, 1) void bigru_all(
    const float* __restrict__ x,
    const float* __restrict__ Wi1, const float* __restrict__ Wh1,
    const float* __restrict__ bi1, const float* __restrict__ bh1,
    const float* __restrict__ Wi5, const float* __restrict__ Wh5,
    const float* __restrict__ bi5, const float* __restrict__ bh5,
    const float* __restrict__ Wc,  const float* __restrict__ bc,
    float* __restrict__ out)
{
    __shared__ __align__(16) _Float16 yb0[2 * YSB];
    __shared__ __align__(16) _Float16 yb1[2 * YSB];
    __shared__ __align__(16) _Float16 xp[4 * XPJ];
    __shared__ __align__(16) float    hb[4 * HB_JOB];
    __shared__ __align__(16) float    xs[2 * T * 4];

    const int lane = threadIdx.x;
    const int j15  = lane & 15;
    const int quad = lane >> 4;
    const int job  = quad;          // 0..3
    const int lb   = job >> 1;      // local batch 0/1
    const int dir  = job & 1;       // 0 fwd, 1 bwd

    // ---- stage x[2][T][3] -> xs[2][T][4]
    {
        const float* xg = x + (size_t)blockIdx.x * (2 * T * F_IN);
        for (int idx = lane; idx < 2 * T * F_IN; idx += 64) {
            int bb = idx / (T * F_IN);
            int r  = idx - bb * (T * F_IN);
            int tt = r / F_IN;
            int c  = r - tt * F_IN;
            xs[bb * (T * 4) + tt * 4 + c] = xg[idx];
        }
    }

    float hj;

    // ================= layer 1 (input width 3, VALU gx) =================
    {
        const float* Wi = Wi1 + dir * (G * F_IN);
        const float* Wh = Wh1 + dir * (G * H);
        const float* bi = bi1 + dir * G;
        const float* bh = bh1 + dir * G;
        float  wi[3][F_IN];
        float4 wh4[3][4];
        float  bir[3], bhr[3];
        #pragma unroll
        for (int g = 0; g < 3; ++g) {
            int row = g * H + j15;
            #pragma unroll
            for (int k = 0; k < F_IN; ++k) wi[g][k] = Wi[row * F_IN + k];
            #pragma unroll
            for (int k = 0; k < 4; ++k)
                wh4[g][k] = ((const float4*)(Wh + row * H))[k];
            bir[g] = bi[row];
            bhr[g] = bh[row];
        }
        hj = 0.0f;
        hb[job * HB_JOB + j15] = 0.0f;

        const float4* x4  = ((const float4*)xs) + lb * T;
        const float4* h4p = (const float4*)(hb + job * HB_JOB);
        _Float16* yw = yb0 + lb * YSB + (dir ? (T - 1) : 0) * YST + dir * H + j15;
        const int ystep = dir ? -YST : YST;

        #pragma unroll 4
        for (int s = 0; s < T; ++s) {
            int t = dir ? (T - 1 - s) : s;
            float4 xv = x4[t];
            float gx0 = fmaf(wi[0][2], xv.z, fmaf(wi[0][1], xv.y, fmaf(wi[0][0], xv.x, bir[0])));
            float gx1 = fmaf(wi[1][2], xv.z, fmaf(wi[1][1], xv.y, fmaf(wi[1][0], xv.x, bir[1])));
            float gx2 = fmaf(wi[2][2], xv.z, fmaf(wi[2][1], xv.y, fmaf(wi[2][0], xv.x, bir[2])));
            float4 hv0 = h4p[0], hv1 = h4p[1], hv2 = h4p[2], hv3 = h4p[3];
            float gh0 = dot4f(wh4[0][3], hv3, dot4f(wh4[0][2], hv2, dot4f(wh4[0][1], hv1, dot4f(wh4[0][0], hv0, bhr[0]))));
            float gh1 = dot4f(wh4[1][3], hv3, dot4f(wh4[1][2], hv2, dot4f(wh4[1][1], hv1, dot4f(wh4[1][0], hv0, bhr[1]))));
            float gh2 = dot4f(wh4[2][3], hv3, dot4f(wh4[2][2], hv2, dot4f(wh4[2][1], hv1, dot4f(wh4[2][0], hv0, bhr[2]))));
            float rg = fast_sigmoid(gx0 + gh0);
            float zg = fast_sigmoid(gx1 + gh1);
            float ng = fast_tanh(fmaf(rg, gh2, gx2));
            float hn = fmaf(zg, hj - ng, ng);
            hj = hn;
            hb[job * HB_JOB + j15] = hn;
            *yw = (_Float16)hn;
            yw += ystep;
        }
    }

    // ================= layers 2..6: MFMA xp + slim recurrence =================
    #pragma unroll 1
    for (int l = 0; l < DEPTH; ++l) {
        const _Float16* yin  = (l & 1) ? yb1 : yb0;
        _Float16*       yout = (l & 1) ? yb0 : yb1;

        // B-frags: bf[d][nt] holds Wi_d[nt*16 + j15][quad*8 + 0..7] as f16
        half8 bf[2][3];
        float bib[2][3];
        #pragma unroll
        for (int d = 0; d < 2; ++d) {
            #pragma unroll
            for (int nt = 0; nt < 3; ++nt) {
                const float* w = Wi5 + ((size_t)(l * 2 + d) * G + nt * 16 + j15) * D2 + quad * 8;
                half8 hv;
                #pragma unroll
                for (int i = 0; i < 8; ++i) hv[i] = (_Float16)w[i];
                bf[d][nt] = hv;
                bib[d][nt] = bi5[(l * 2 + d) * G + nt * 16 + j15];
            }
        }
        // recurrent weights for this lane's own job
        float4 wh4[3][4];
        float  bhr[3];
        {
            const float* WhL = Wh5 + (size_t)(l * 2 + dir) * G * H;
            const float* bhL = bh5 + (l * 2 + dir) * G;
            #pragma unroll
            for (int g = 0; g < 3; ++g) {
                int row = g * H + j15;
                #pragma unroll
                for (int k = 0; k < 4; ++k)
                    wh4[g][k] = ((const float4*)(WhL + row * H))[k];
                bhr[g] = bhL[row];
            }
        }
        hj = 0.0f;
        hb[job * HB_JOB + j15] = 0.0f;

        #pragma unroll 1
        for (int c = 0; c < 4; ++c) {
            const int s0 = c * TC;
            // ---- xp chunk via MFMA: for each job, XP[tb..tb+15][48 gates] ----
            #pragma unroll
            for (int jb = 0; jb < 4; ++jb) {
                const int db = jb & 1, bb = jb >> 1;
                const int tb = db ? (T - TC - s0) : s0;
                half8 a = *(const half8*)(yin + bb * YSB + (tb + j15) * YST + quad * 8);
                f32x4v c0 = {0.f,0.f,0.f,0.f}, c1 = {0.f,0.f,0.f,0.f}, c2 = {0.f,0.f,0.f,0.f};
                c0 = __builtin_amdgcn_mfma_f32_16x16x32_f16(a, bf[db][0], c0, 0, 0, 0);
                c1 = __builtin_amdgcn_mfma_f32_16x16x32_f16(a, bf[db][1], c1, 0, 0, 0);
                c2 = __builtin_amdgcn_mfma_f32_16x16x32_f16(a, bf[db][2], c2, 0, 0, 0);
                // C layout: col(j15) = gate-within-tile, row(quad*4+r) = t-tb
                _Float16* xw = xp + jb * XPJ + (quad * 4) * 64 + j15 * 4;
                #pragma unroll
                for (int r = 0; r < 4; ++r) {
                    half4v v;
                    v[0] = (_Float16)(c0[r] + bib[db][0]);
                    v[1] = (_Float16)(c1[r] + bib[db][1]);
                    v[2] = (_Float16)(c2[r] + bib[db][2]);
                    v[3] = (_Float16)0.0f;
                    *(half4v*)(xw + r * 64) = v;
                }
            }

            // ---- 16 recurrent steps (no barriers: single-wave lockstep) ----
            const _Float16* xr = xp + job * XPJ + (dir ? (TC - 1) : 0) * 64 + j15 * 4;
            const int t0 = dir ? (T - 1 - s0) : s0;
            _Float16* yw = yout + lb * YSB + t0 * YST + dir * H + j15;
            const int xstep = dir ? -64 : 64;
            const int ystep = dir ? -YST : YST;
            const float4* h4p = (const float4*)(hb + job * HB_JOB);

            #pragma unroll 4
            for (int cl = 0; cl < TC; ++cl) {
                half4v gx = *(const half4v*)xr;
                float gx0 = (float)gx[0], gx1 = (float)gx[1], gx2 = (float)gx[2];
                float4 hv0 = h4p[0], hv1 = h4p[1], hv2 = h4p[2], hv3 = h4p[3];
                float gh0 = dot4f(wh4[0][3], hv3, dot4f(wh4[0][2], hv2, dot4f(wh4[0][1], hv1, dot4f(wh4[0][0], hv0, bhr[0]))));
                float gh1 = dot4f(wh4[1][3], hv3, dot4f(wh4[1][2], hv2, dot4f(wh4[1][1], hv1, dot4f(wh4[1][0], hv0, bhr[1]))));
                float gh2 = dot4f(wh4[2][3], hv3, dot4f(wh4[2][2], hv2, dot4f(wh4[2][1], hv1, dot4f(wh4[2][0], hv0, bhr[2]))));
                float rg = fast_sigmoid(gx0 + gh0);
                float zg = fast_sigmoid(gx1 + gh1);
                float ng = fast_tanh(fmaf(rg, gh2, gx2));
                float hn = fmaf(zg, hj - ng, ng);
                hj = hn;
                hb[job * HB_JOB + j15] = hn;
                *yw = (_Float16)hn;
                xr += xstep;
                yw += ystep;
            }
        }
    }

    // ================= classifier + softmax (final y in yb1) =================
    #pragma unroll
    for (int i = 0; i < 2; ++i) {
        int idx = lane + i * 64;
        int bb  = idx >> 6;
        int t   = idx & 63;
        const _Float16* yrow = yb1 + bb * YSB + t * YST;
        float yv[D2];
        #pragma unroll
        for (int k = 0; k < D2; ++k) yv[k] = (float)yrow[k];
        float lg[NCLS];
        #pragma unroll
        for (int c = 0; c < NCLS; ++c) {
            const float* wc = Wc + c * D2;
            float acc = bc[c];
            #pragma unroll
            for (int k = 0; k < D2; ++k) acc = fmaf(wc[k], yv[k], acc);
            lg[c] = acc;
        }
        float m = fmaxf(fmaxf(lg[0], lg[1]), fmaxf(lg[2], lg[3]));
        float e0 = __expf(lg[0] - m), e1 = __expf(lg[1] - m);
        float e2 = __expf(lg[2] - m), e3 = __expf(lg[3] - m);
        float inv = __fdividef(1.0f, e0 + e1 + e2 + e3);
        size_t bglob = (size_t)blockIdx.x * 2 + bb;
        float4 o;
        o.x = e0 * inv; o.y = e1 * inv; o.z = e2 * inv; o.w = e3 * inv;
        ((float4*)out)[bglob * T + t] = o;
    }
}

extern "C" void kernel_launch(void* const* d_in, const int* in_sizes, int n_in,
                              void* d_out, int out_size, void* d_ws, size_t ws_size,
                              hipStream_t stream) {
    const float* x   = (const float*)d_in[0];
    const float* Wi1 = (const float*)d_in[1];
    const float* Wh1 = (const float*)d_in[2];
    const float* bi1 = (const float*)d_in[3];
    const float* bh1 = (const float*)d_in[4];
    const float* Wi5 = (const float*)d_in[5];
    const float* Wh5 = (const float*)d_in[6];
    const float* bi5 = (const float*)d_in[7];
    const float* bh5 = (const float*)d_in[8];
    const float* Wc  = (const float*)d_in[9];
    const float* bc  = (const float*)d_in[10];
    float* out = (float*)d_out;

    const int B = in_sizes[0] / (T * F_IN);   // 16384
    dim3 grid(B / 2), block(64);
    hipLaunchKernelGGL(bigru_all, grid, block, 0, stream,
                       x, Wi1, Wh1, bi1, bh1, Wi5, Wh5, bi5, bh5, Wc, bc, out);
}

// Round 4
// 662.193 us; speedup vs baseline: 2.6113x; 1.4902x over previous
//
#include <hip/hip_runtime.h>

#define T 64
#define F_IN 3
#define H 16
#define G 48
#define D2 32
#define DEPTH 5
#define NCLS 4

// LDS geometry (element units)
#define YST 32          // f16 per t-row (rows are 64 B, 16B-aligned)
#define YSB 2056        // f16 per batch elem (64*32 + 8 pad; keeps 16B align, shifts banks)
#define HB_JOB 20       // f32 per job in hbuf (16 + 4 pad -> per-job bank spread)

typedef _Float16 half8 __attribute__((ext_vector_type(8)));
typedef float f32x4v __attribute__((ext_vector_type(4)));

__device__ __forceinline__ float fast_sigmoid(float x) {
    return __fdividef(1.0f, 1.0f + __expf(-x));
}
__device__ __forceinline__ float fast_tanh(float x) {
    return 1.0f - __fdividef(2.0f, 1.0f + __expf(2.0f * x));
}
__device__ __forceinline__ float dot4f(float4 a, float4 b, float acc) {
    acc = fmaf(a.x, b.x, acc); acc = fmaf(a.y, b.y, acc);
    acc = fmaf(a.z, b.z, acc); acc = fmaf(a.w, b.w, acc);
    return acc;
}

// One wave per WG. Job mapping (NEW): job = quad, lb = quad&1, dir = quad>>1.
// This matches the MFMA C-layout trick below: per 4-timestep chunk, two sets of
// 3 MFMAs (one per direction) with A-rows m = (dir? 8:0) + lb*4 + tl produce
// gx[job][t][gate] DIRECTLY in lane (quad=job, j15=gate), reg r = tl.
// No xp LDS buffer, no per-step gx read. Whole WG is one wave -> lockstep,
// no __syncthreads() anywhere.
__global__ __launch_bounds__(64, 2) void bigru_all(
    const float* __restrict__ x,
    const float* __restrict__ Wi1, const float* __restrict__ Wh1,
    const float* __restrict__ bi1, const float* __restrict__ bh1,
    const float* __restrict__ Wi5, const float* __restrict__ Wh5,
    const float* __restrict__ bi5, const float* __restrict__ bh5,
    const float* __restrict__ Wc,  const float* __restrict__ bc,
    float* __restrict__ out)
{
    __shared__ __align__(16) _Float16 yb0[2 * YSB];
    __shared__ __align__(16) _Float16 yb1[2 * YSB];
    __shared__ __align__(16) float    hb[4 * HB_JOB];
    __shared__ __align__(16) float    xs[2 * T * 4];

    const int lane = threadIdx.x;
    const int j15  = lane & 15;
    const int quad = lane >> 4;
    const int job  = quad;
    const int lb   = quad & 1;
    const int dir  = quad >> 1;
    const bool isf = (dir == 0);

    // ---- stage x[2][T][3] -> xs[2][T][4]
    {
        const float* xg = x + (size_t)blockIdx.x * (2 * T * F_IN);
        for (int idx = lane; idx < 2 * T * F_IN; idx += 64) {
            int bb = idx / (T * F_IN);
            int r  = idx - bb * (T * F_IN);
            int tt = r / F_IN;
            int c  = r - tt * F_IN;
            xs[bb * (T * 4) + tt * 4 + c] = xg[idx];
        }
    }

    float hj;

    // ================= layer 1 (input width 3, VALU gx) =================
    {
        const float* Wi = Wi1 + dir * (G * F_IN);
        const float* Wh = Wh1 + dir * (G * H);
        const float* bi = bi1 + dir * G;
        const float* bh = bh1 + dir * G;
        float  wi[3][F_IN];
        float4 wh4[3][4];
        float  bir[3], bhr[3];
        #pragma unroll
        for (int g = 0; g < 3; ++g) {
            int row = g * H + j15;
            #pragma unroll
            for (int k = 0; k < F_IN; ++k) wi[g][k] = Wi[row * F_IN + k];
            #pragma unroll
            for (int k = 0; k < 4; ++k)
                wh4[g][k] = ((const float4*)(Wh + row * H))[k];
            bir[g] = bi[row];
            bhr[g] = bh[row];
        }
        hj = 0.0f;
        hb[job * HB_JOB + j15] = 0.0f;

        const float4* x4  = ((const float4*)xs) + lb * T;
        const float4* h4p = (const float4*)(hb + job * HB_JOB);
        _Float16* yw = yb0 + lb * YSB + (isf ? 0 : (T - 1)) * YST + dir * H + j15;
        const int ystep = isf ? YST : -YST;

        #pragma unroll 4
        for (int s = 0; s < T; ++s) {
            int t = isf ? s : (T - 1 - s);
            float4 xv = x4[t];
            float gx0 = fmaf(wi[0][2], xv.z, fmaf(wi[0][1], xv.y, fmaf(wi[0][0], xv.x, bir[0])));
            float gx1 = fmaf(wi[1][2], xv.z, fmaf(wi[1][1], xv.y, fmaf(wi[1][0], xv.x, bir[1])));
            float gx2 = fmaf(wi[2][2], xv.z, fmaf(wi[2][1], xv.y, fmaf(wi[2][0], xv.x, bir[2])));
            float4 hv0 = h4p[0], hv1 = h4p[1], hv2 = h4p[2], hv3 = h4p[3];
            float gh0 = dot4f(wh4[0][3], hv3, dot4f(wh4[0][2], hv2, dot4f(wh4[0][1], hv1, dot4f(wh4[0][0], hv0, bhr[0]))));
            float gh1 = dot4f(wh4[1][3], hv3, dot4f(wh4[1][2], hv2, dot4f(wh4[1][1], hv1, dot4f(wh4[1][0], hv0, bhr[1]))));
            float gh2 = dot4f(wh4[2][3], hv3, dot4f(wh4[2][2], hv2, dot4f(wh4[2][1], hv1, dot4f(wh4[2][0], hv0, bhr[2]))));
            float rg = fast_sigmoid(gx0 + gh0);
            float zg = fast_sigmoid(gx1 + gh1);
            float ng = fast_tanh(fmaf(rg, gh2, gx2));
            float hn = fmaf(zg, hj - ng, ng);
            hj = hn;
            hb[job * HB_JOB + j15] = hn;
            *yw = (_Float16)hn;
            yw += ystep;
        }
    }

    // ================= layers 2..6: register-gx MFMA + slim recurrence ======
    #pragma unroll 1
    for (int l = 0; l < DEPTH; ++l) {
        const _Float16* yin  = (l & 1) ? yb1 : yb0;
        _Float16*       yout = (l & 1) ? yb0 : yb1;

        // B-frags for BOTH dirs: bf[d][g] = Wi_d[g*16 + j15][quad*8 + 0..7]
        half8 bf[2][3];
        #pragma unroll
        for (int d = 0; d < 2; ++d) {
            #pragma unroll
            for (int g = 0; g < 3; ++g) {
                const float* w = Wi5 + ((size_t)(l * 2 + d) * G + g * 16 + j15) * D2 + quad * 8;
                half8 hv;
                #pragma unroll
                for (int i = 0; i < 8; ++i) hv[i] = (_Float16)w[i];
                bf[d][g] = hv;
            }
        }
        // own-dir bias + recurrent weights
        float bib[3], bhr[3];
        float4 wh4[3][4];
        {
            const float* WhL = Wh5 + (size_t)(l * 2 + dir) * G * H;
            const float* bhL = bh5 + (l * 2 + dir) * G;
            const float* biL = bi5 + (l * 2 + dir) * G;
            #pragma unroll
            for (int g = 0; g < 3; ++g) {
                int row = g * H + j15;
                #pragma unroll
                for (int k = 0; k < 4; ++k)
                    wh4[g][k] = ((const float4*)(WhL + row * H))[k];
                bhr[g] = bhL[row];
                bib[g] = biL[row];
            }
        }
        hj = 0.0f;
        hb[job * HB_JOB + j15] = 0.0f;

        const float4* h4p = (const float4*)(hb + job * HB_JOB);
        // A-frag row for this lane (fixed role per chunk):
        //   j15<8  -> supplies fwd rows m=j15      : batch (j15>>2)&1, tl=j15&3
        //   j15>=8 -> supplies bwd rows m=j15      : batch (j15>>2)&1, tl=j15&3
        const int lb_a = (j15 >> 2) & 1;
        const int tl_a = j15 & 3;

        #pragma unroll 1
        for (int c = 0; c < T / 4; ++c) {
            const int tf = 4 * c;
            const int tb = T - 4 - 4 * c;
            const int row = (j15 < 8) ? (tf + tl_a) : (tb + tl_a);
            half8 a = *(const half8*)(yin + lb_a * YSB + row * YST + quad * 8);
            f32x4v z4 = {0.f, 0.f, 0.f, 0.f};
            f32x4v c0f = __builtin_amdgcn_mfma_f32_16x16x32_f16(a, bf[0][0], z4, 0, 0, 0);
            f32x4v c1f = __builtin_amdgcn_mfma_f32_16x16x32_f16(a, bf[0][1], z4, 0, 0, 0);
            f32x4v c2f = __builtin_amdgcn_mfma_f32_16x16x32_f16(a, bf[0][2], z4, 0, 0, 0);
            f32x4v c0b = __builtin_amdgcn_mfma_f32_16x16x32_f16(a, bf[1][0], z4, 0, 0, 0);
            f32x4v c1b = __builtin_amdgcn_mfma_f32_16x16x32_f16(a, bf[1][1], z4, 0, 0, 0);
            f32x4v c2b = __builtin_amdgcn_mfma_f32_16x16x32_f16(a, bf[1][2], z4, 0, 0, 0);
            // per-lane gx for the 4 steps of this chunk (step s: fwd reg s, bwd reg 3-s)
            float gx0[4], gx1[4], gx2[4];
            #pragma unroll
            for (int s = 0; s < 4; ++s) {
                gx0[s] = (isf ? c0f[s] : c0b[3 - s]) + bib[0];
                gx1[s] = (isf ? c1f[s] : c1b[3 - s]) + bib[1];
                gx2[s] = (isf ? c2f[s] : c2b[3 - s]) + bib[2];
            }
            _Float16* yw = yout + lb * YSB + (isf ? tf : (T - 1 - 4 * c)) * YST + dir * H + j15;
            const int ystep = isf ? YST : -YST;

            #pragma unroll
            for (int s = 0; s < 4; ++s) {
                float4 hv0 = h4p[0], hv1 = h4p[1], hv2 = h4p[2], hv3 = h4p[3];
                float gh0 = dot4f(wh4[0][3], hv3, dot4f(wh4[0][2], hv2, dot4f(wh4[0][1], hv1, dot4f(wh4[0][0], hv0, bhr[0]))));
                float gh1 = dot4f(wh4[1][3], hv3, dot4f(wh4[1][2], hv2, dot4f(wh4[1][1], hv1, dot4f(wh4[1][0], hv0, bhr[1]))));
                float gh2 = dot4f(wh4[2][3], hv3, dot4f(wh4[2][2], hv2, dot4f(wh4[2][1], hv1, dot4f(wh4[2][0], hv0, bhr[2]))));
                float rg = fast_sigmoid(gx0[s] + gh0);
                float zg = fast_sigmoid(gx1[s] + gh1);
                float ng = fast_tanh(fmaf(rg, gh2, gx2[s]));
                float hn = fmaf(zg, hj - ng, ng);
                hj = hn;
                hb[job * HB_JOB + j15] = hn;
                *yw = (_Float16)hn;
                yw += ystep;
            }
        }
    }

    // ================= classifier + softmax (final y in yb1) =================
    #pragma unroll
    for (int i = 0; i < 2; ++i) {
        int idx = lane + i * 64;
        int bb  = idx >> 6;
        int t   = idx & 63;
        const _Float16* yrow = yb1 + bb * YSB + t * YST;
        float yv[D2];
        #pragma unroll
        for (int k8 = 0; k8 < 4; ++k8) {
            half8 v = *(const half8*)(yrow + k8 * 8);
            #pragma unroll
            for (int i8 = 0; i8 < 8; ++i8) yv[k8 * 8 + i8] = (float)v[i8];
        }
        float lg[NCLS];
        #pragma unroll
        for (int c = 0; c < NCLS; ++c) {
            const float* wc = Wc + c * D2;
            float acc = bc[c];
            #pragma unroll
            for (int k = 0; k < D2; ++k) acc = fmaf(wc[k], yv[k], acc);
            lg[c] = acc;
        }
        float m = fmaxf(fmaxf(lg[0], lg[1]), fmaxf(lg[2], lg[3]));
        float e0 = __expf(lg[0] - m), e1 = __expf(lg[1] - m);
        float e2 = __expf(lg[2] - m), e3 = __expf(lg[3] - m);
        float inv = __fdividef(1.0f, e0 + e1 + e2 + e3);
        size_t bglob = (size_t)blockIdx.x * 2 + bb;
        float4 o;
        o.x = e0 * inv; o.y = e1 * inv; o.z = e2 * inv; o.w = e3 * inv;
        ((float4*)out)[bglob * T + t] = o;
    }
}

extern "C" void kernel_launch(void* const* d_in, const int* in_sizes, int n_in,
                              void* d_out, int out_size, void* d_ws, size_t ws_size,
                              hipStream_t stream) {
    const float* x   = (const float*)d_in[0];
    const float* Wi1 = (const float*)d_in[1];
    const float* Wh1 = (const float*)d_in[2];
    const float* bi1 = (const float*)d_in[3];
    const float* bh1 = (const float*)d_in[4];
    const float* Wi5 = (const float*)d_in[5];
    const float* Wh5 = (const float*)d_in[6];
    const float* bi5 = (const float*)d_in[7];
    const float* bh5 = (const float*)d_in[8];
    const float* Wc  = (const float*)d_in[9];
    const float* bc  = (const float*)d_in[10];
    float* out = (float*)d_out;

    const int B = in_sizes[0] / (T * F_IN);   // 16384
    dim3 grid(B / 2), block(64);
    hipLaunchKernelGGL(bigru_all, grid, block, 0, stream,
                       x, Wi1, Wh1, bi1, bh1, Wi5, Wh5, bi5, bh5, Wc, bc, out);
}

// Round 5
// 538.750 us; speedup vs baseline: 3.2097x; 1.2291x over previous
//
#include <hip/hip_runtime.h>

#define T 64
#define F_IN 3
#define H 16
#define G 48
#define D2 32
#define DEPTH 5
#define NCLS 4

// LDS geometry (element units)
#define YST 32          // f16 per t-row (64 B rows, 16B-aligned)
#define YSB 2056        // f16 per batch elem (64*32 + 8 pad)
#define HZ_ZOFF 64      // start of the 8-f16 zero block inside hzb

typedef _Float16 half8 __attribute__((ext_vector_type(8)));
typedef float f32x4v __attribute__((ext_vector_type(4)));

__device__ __forceinline__ float fast_sigmoid(float x) {
    return __fdividef(1.0f, 1.0f + __expf(-x));
}
__device__ __forceinline__ float fast_tanh(float x) {
    return 1.0f - __fdividef(2.0f, 1.0f + __expf(2.0f * x));
}

// One wave per WG, 4 jobs: job = quad, lb = quad&1, dir = quad>>1.
// gx (input transform): per-4-step chunk, 6 MFMAs put gx[job][t][gate]
//   directly into the consuming lane's registers (round-4 scheme).
// gh (recurrent transform, NEW): per step, ONE ds_read_b128 of h (f16,
//   from hzb) + 3 MFMAs. A rows 4j..4j+3 = job j's h; direction handled in
//   K-space: fwd jobs' h occupies k<16 (quads 0,1), bwd k>=16 (quads 2,3),
//   invalid half reads a zero block; B packs Wh_fwd (k<16) / Wh_bwd (k>=16).
//   D[m=4*quad][n=j15] (reg 0) = gh[job=quad][gate j15] -- exactly the lane
//   that runs the gate math. Wh.h leaves the VALU entirely.
// Single wave => lockstep => no __syncthreads() anywhere.
__global__ __launch_bounds__(64, 2) void bigru_all(
    const float* __restrict__ x,
    const float* __restrict__ Wi1, const float* __restrict__ Wh1,
    const float* __restrict__ bi1, const float* __restrict__ bh1,
    const float* __restrict__ Wi5, const float* __restrict__ Wh5,
    const float* __restrict__ bi5, const float* __restrict__ bh5,
    const float* __restrict__ Wc,  const float* __restrict__ bc,
    float* __restrict__ out)
{
    __shared__ __align__(16) _Float16 yb0[2 * YSB];
    __shared__ __align__(16) _Float16 yb1[2 * YSB];
    __shared__ __align__(16) _Float16 hzb[80];   // [0,64): h[job][16]; [64,72): zeros
    __shared__ __align__(16) float    xs[2 * T * 4];

    const int lane = threadIdx.x;
    const int j15  = lane & 15;
    const int quad = lane >> 4;
    const int lb   = quad & 1;
    const int dir  = quad >> 1;
    const bool isf = (dir == 0);

    // ---- stage x[2][T][3] -> xs[2][T][4]; zero h + zero block
    {
        const float* xg = x + (size_t)blockIdx.x * (2 * T * F_IN);
        for (int idx = lane; idx < 2 * T * F_IN; idx += 64) {
            int bb = idx / (T * F_IN);
            int r  = idx - bb * (T * F_IN);
            int tt = r / F_IN;
            int c  = r - tt * F_IN;
            xs[bb * (T * 4) + tt * 4 + c] = xg[idx];
        }
        hzb[lane] = (_Float16)0.0f;
        if (lane < 16) hzb[64 + lane] = (_Float16)0.0f;
    }

    // A-frag source for the gh MFMA (loop-invariant):
    // lane supplies A[m=j15][k=quad*8+0..7]; job_a = j15>>2, its dir = j15>>3.
    // valid half: fwd -> quads 0,1 (k<16); bwd -> quads 2,3 (k>=16).
    const int  job_a  = j15 >> 2;
    const bool avalid = ((j15 >> 3) == 0) ? (quad < 2) : (quad >= 2);
    const _Float16* aptr = hzb + (avalid ? (job_a * 16 + (quad & 1) * 8) : HZ_ZOFF);

    float hj;

    // ================= layer 1 (gx scalar, gh via MFMA) =================
    {
        // B-frags: quads 0,1 <- Wh1[fwd] k=quad*8..; quads 2,3 <- Wh1[bwd]
        half8 whB[3];
        {
            const float* wsrc = Wh1 + ((quad < 2) ? 0 : G * H);
            #pragma unroll
            for (int g = 0; g < 3; ++g) {
                const float* w = wsrc + (g * 16 + j15) * H + (quad & 1) * 8;
                half8 hv;
                #pragma unroll
                for (int i = 0; i < 8; ++i) hv[i] = (_Float16)w[i];
                whB[g] = hv;
            }
        }
        float  wi[3][F_IN];
        float  bir[3], bhr2;
        {
            const float* Wi = Wi1 + dir * (G * F_IN);
            const float* bi = bi1 + dir * G;
            const float* bh = bh1 + dir * G;
            #pragma unroll
            for (int g = 0; g < 3; ++g) {
                int row = g * H + j15;
                #pragma unroll
                for (int k = 0; k < F_IN; ++k) wi[g][k] = Wi[row * F_IN + k];
                bir[g] = bi[row] + ((g < 2) ? bh[row] : 0.0f);
            }
            bhr2 = bh[2 * H + j15];
        }
        hj = 0.0f;

        const float4* x4 = ((const float4*)xs) + lb * T;
        _Float16* yw = yb0 + lb * YSB + (isf ? 0 : (T - 1)) * YST + dir * H + j15;
        const int ystep = isf ? YST : -YST;

        #pragma unroll 2
        for (int s = 0; s < T; ++s) {
            int t = isf ? s : (T - 1 - s);
            float4 xv = x4[t];
            float gxr = fmaf(wi[0][2], xv.z, fmaf(wi[0][1], xv.y, fmaf(wi[0][0], xv.x, bir[0])));
            float gxz = fmaf(wi[1][2], xv.z, fmaf(wi[1][1], xv.y, fmaf(wi[1][0], xv.x, bir[1])));
            float gxn = fmaf(wi[2][2], xv.z, fmaf(wi[2][1], xv.y, fmaf(wi[2][0], xv.x, bir[2])));
            half8 a = *(const half8*)aptr;
            f32x4v z4 = {0.f, 0.f, 0.f, 0.f};
            f32x4v d0 = __builtin_amdgcn_mfma_f32_16x16x32_f16(a, whB[0], z4, 0, 0, 0);
            f32x4v d1 = __builtin_amdgcn_mfma_f32_16x16x32_f16(a, whB[1], z4, 0, 0, 0);
            f32x4v d2 = __builtin_amdgcn_mfma_f32_16x16x32_f16(a, whB[2], z4, 0, 0, 0);
            float rg = fast_sigmoid(gxr + d0[0]);
            float zg = fast_sigmoid(gxz + d1[0]);
            float ng = fast_tanh(fmaf(rg, d2[0] + bhr2, gxn));
            float hn = fmaf(zg, hj - ng, ng);
            hj = hn;
            _Float16 hh = (_Float16)hn;
            hzb[lane] = hh;          // lane == job*16 + j15
            *yw = hh;
            yw += ystep;
        }
    }

    // ================= layers 2..6 =================
    #pragma unroll 1
    for (int l = 0; l < DEPTH; ++l) {
        const _Float16* yin  = (l & 1) ? yb1 : yb0;
        _Float16*       yout = (l & 1) ? yb0 : yb1;

        // gx B-frags (both dirs): bf[d][g] = Wi_d[g*16+j15][quad*8+0..7]
        half8 bf[2][3];
        #pragma unroll
        for (int d = 0; d < 2; ++d) {
            #pragma unroll
            for (int g = 0; g < 3; ++g) {
                const float* w = Wi5 + ((size_t)(l * 2 + d) * G + g * 16 + j15) * D2 + quad * 8;
                half8 hv;
                #pragma unroll
                for (int i = 0; i < 8; ++i) hv[i] = (_Float16)w[i];
                bf[d][g] = hv;
            }
        }
        // gh B-frags: dir split by quad-half
        half8 whB[3];
        {
            const float* wsrc = Wh5 + (size_t)(l * 2) * G * H + ((quad < 2) ? 0 : G * H);
            #pragma unroll
            for (int g = 0; g < 3; ++g) {
                const float* w = wsrc + (g * 16 + j15) * H + (quad & 1) * 8;
                half8 hv;
                #pragma unroll
                for (int i = 0; i < 8; ++i) hv[i] = (_Float16)w[i];
                whB[g] = hv;
            }
        }
        // own-dir biases; bh folded into gates r,z; bh_n kept separate
        float bib[3], bhr2;
        {
            const float* biL = bi5 + (l * 2 + dir) * G;
            const float* bhL = bh5 + (l * 2 + dir) * G;
            bib[0] = biL[j15]          + bhL[j15];
            bib[1] = biL[H + j15]      + bhL[H + j15];
            bib[2] = biL[2 * H + j15];
            bhr2   = bhL[2 * H + j15];
        }
        hj = 0.0f;
        hzb[lane] = (_Float16)0.0f;

        // gx A-frag role (fixed): rows m = dir*8 + lb*4 + tl
        const int lb_a = (j15 >> 2) & 1;
        const int tl_a = j15 & 3;

        #pragma unroll 1
        for (int c = 0; c < T / 4; ++c) {
            const int tf = 4 * c;
            const int tb = T - 4 - 4 * c;
            const int row = (j15 < 8) ? (tf + tl_a) : (tb + tl_a);
            half8 ax = *(const half8*)(yin + lb_a * YSB + row * YST + quad * 8);
            f32x4v z4 = {0.f, 0.f, 0.f, 0.f};
            f32x4v c0f = __builtin_amdgcn_mfma_f32_16x16x32_f16(ax, bf[0][0], z4, 0, 0, 0);
            f32x4v c1f = __builtin_amdgcn_mfma_f32_16x16x32_f16(ax, bf[0][1], z4, 0, 0, 0);
            f32x4v c2f = __builtin_amdgcn_mfma_f32_16x16x32_f16(ax, bf[0][2], z4, 0, 0, 0);
            f32x4v c0b = __builtin_amdgcn_mfma_f32_16x16x32_f16(ax, bf[1][0], z4, 0, 0, 0);
            f32x4v c1b = __builtin_amdgcn_mfma_f32_16x16x32_f16(ax, bf[1][1], z4, 0, 0, 0);
            f32x4v c2b = __builtin_amdgcn_mfma_f32_16x16x32_f16(ax, bf[1][2], z4, 0, 0, 0);
            float gx0[4], gx1[4], gx2[4];
            #pragma unroll
            for (int s = 0; s < 4; ++s) {
                gx0[s] = (isf ? c0f[s] : c0b[3 - s]) + bib[0];
                gx1[s] = (isf ? c1f[s] : c1b[3 - s]) + bib[1];
                gx2[s] = (isf ? c2f[s] : c2b[3 - s]) + bib[2];
            }
            _Float16* yw = yout + lb * YSB + (isf ? tf : (T - 1 - 4 * c)) * YST + dir * H + j15;
            const int ystep = isf ? YST : -YST;

            #pragma unroll
            for (int s = 0; s < 4; ++s) {
                half8 a = *(const half8*)aptr;
                f32x4v z4b = {0.f, 0.f, 0.f, 0.f};
                f32x4v d0 = __builtin_amdgcn_mfma_f32_16x16x32_f16(a, whB[0], z4b, 0, 0, 0);
                f32x4v d1 = __builtin_amdgcn_mfma_f32_16x16x32_f16(a, whB[1], z4b, 0, 0, 0);
                f32x4v d2 = __builtin_amdgcn_mfma_f32_16x16x32_f16(a, whB[2], z4b, 0, 0, 0);
                float rg = fast_sigmoid(gx0[s] + d0[0]);
                float zg = fast_sigmoid(gx1[s] + d1[0]);
                float ng = fast_tanh(fmaf(rg, d2[0] + bhr2, gx2[s]));
                float hn = fmaf(zg, hj - ng, ng);
                hj = hn;
                _Float16 hh = (_Float16)hn;
                hzb[lane] = hh;
                *yw = hh;
                yw += ystep;
            }
        }
    }

    // ================= classifier + softmax (final y in yb1) =================
    #pragma unroll
    for (int i = 0; i < 2; ++i) {
        int idx = lane + i * 64;
        int bb  = idx >> 6;
        int t   = idx & 63;
        const _Float16* yrow = yb1 + bb * YSB + t * YST;
        float yv[D2];
        #pragma unroll
        for (int k8 = 0; k8 < 4; ++k8) {
            half8 v = *(const half8*)(yrow + k8 * 8);
            #pragma unroll
            for (int i8 = 0; i8 < 8; ++i8) yv[k8 * 8 + i8] = (float)v[i8];
        }
        float lg[NCLS];
        #pragma unroll
        for (int c = 0; c < NCLS; ++c) {
            const float* wc = Wc + c * D2;
            float acc = bc[c];
            #pragma unroll
            for (int k = 0; k < D2; ++k) acc = fmaf(wc[k], yv[k], acc);
            lg[c] = acc;
        }
        float m = fmaxf(fmaxf(lg[0], lg[1]), fmaxf(lg[2], lg[3]));
        float e0 = __expf(lg[0] - m), e1 = __expf(lg[1] - m);
        float e2 = __expf(lg[2] - m), e3 = __expf(lg[3] - m);
        float inv = __fdividef(1.0f, e0 + e1 + e2 + e3);
        size_t bglob = (size_t)blockIdx.x * 2 + bb;
        float4 o;
        o.x = e0 * inv; o.y = e1 * inv; o.z = e2 * inv; o.w = e3 * inv;
        ((float4*)out)[bglob * T + t] = o;
    }
}

extern "C" void kernel_launch(void* const* d_in, const int* in_sizes, int n_in,
                              void* d_out, int out_size, void* d_ws, size_t ws_size,
                              hipStream_t stream) {
    const float* x   = (const float*)d_in[0];
    const float* Wi1 = (const float*)d_in[1];
    const float* Wh1 = (const float*)d_in[2];
    const float* bi1 = (const float*)d_in[3];
    const float* bh1 = (const float*)d_in[4];
    const float* Wi5 = (const float*)d_in[5];
    const float* Wh5 = (const float*)d_in[6];
    const float* bi5 = (const float*)d_in[7];
    const float* bh5 = (const float*)d_in[8];
    const float* Wc  = (const float*)d_in[9];
    const float* bc  = (const float*)d_in[10];
    float* out = (float*)d_out;

    const int B = in_sizes[0] / (T * F_IN);   // 16384
    dim3 grid(B / 2), block(64);
    hipLaunchKernelGGL(bigru_all, grid, block, 0, stream,
                       x, Wi1, Wh1, bi1, bh1, Wi5, Wh5, bi5, bh5, Wc, bc, out);
}